// Round 4
// baseline (1386.425 us; speedup 1.0000x reference)
//
#include <hip/hip_runtime.h>
#include <hip/hip_fp16.h>

typedef _Float16 f16;
typedef _Float16 f16x8 __attribute__((ext_vector_type(8)));
typedef _Float16 f16x4 __attribute__((ext_vector_type(4)));
typedef float f32x4 __attribute__((ext_vector_type(4)));

#define L2E 1.4426950408889634f

// workspace layout (bytes)
#define WQ_OFF   0         // 768*256 f16   qkv weight, row-major [n][k]
#define PW_OFF   393216    // 256*256 f16   proj weight, row-major [n][k]
#define QB_OFF   524288    // 768 f32       concat qkv bias (k-bias = 0)
#define SC_OFF   527360    // 8 f32         exp(min(logit_scale, ln100))
#define TBL_OFF  527616    // 225*8 f32     cpb mlp table
#define BB_OFF   535040    // 32768 f32     folded bias, permuted [h][mi][nj][c][g][r]

// ---------------- prep kernels ----------------

__global__ void prep0(const float* __restrict__ qw, const float* __restrict__ prw,
                      const float* __restrict__ qbias, const float* __restrict__ vbias,
                      const float* __restrict__ ls, char* __restrict__ ws) {
    int t = blockIdx.x * 256 + threadIdx.x;
    f16* wq = (f16*)(ws + WQ_OFF);
    f16* pw = (f16*)(ws + PW_OFF);
    if (t < 196608) wq[t] = (f16)qw[t];
    else            pw[t - 196608] = (f16)prw[t - 196608];
    if (t < 768) {
        float b = t < 256 ? qbias[t] : (t < 512 ? 0.f : vbias[t - 512]);
        ((float*)(ws + QB_OFF))[t] = b;
    }
    if (t < 8) ((float*)(ws + SC_OFF))[t] = expf(fminf(ls[t], 4.6051701859880914f));
}

__device__ __forceinline__ float norm_coord(int u) { // u in 0..14
    float v = (float)(u - 7) * (8.0f / 7.0f);
    float s = (v > 0.f) ? 1.f : ((v < 0.f) ? -1.f : 0.f);
    return s * log2f(fabsf(v) + 1.f) * (1.f / 3.f);
}

__global__ void prep1(const float* __restrict__ w1, const float* __restrict__ b1,
                      const float* __restrict__ w2, char* __restrict__ ws) {
    int t = blockIdx.x * 256 + threadIdx.x; // 1800 used
    if (t >= 1800) return;
    int p = t >> 3, h = t & 7;
    float ta = norm_coord(p / 15);
    float tb = norm_coord(p % 15);
    float acc = 0.f;
    for (int j = 0; j < 512; ++j) {
        float hv = fmaf(w1[2 * j], ta, fmaf(w1[2 * j + 1], tb, b1[j]));
        acc = fmaf(fmaxf(hv, 0.f), w2[h * 512 + j], acc);
    }
    ((float*)(ws + TBL_OFF))[p * 8 + h] = acc;
}

__global__ void prep2(char* __restrict__ ws) {
    int t = blockIdx.x * 256 + threadIdx.x; // 32768 = 8*64*64
    int h = t >> 12, i = (t >> 6) & 63, j = t & 63;
    int ri = ((i >> 3) - (j >> 3) + 7) * 15 + ((i & 7) - (j & 7) + 7);
    float bv = ((const float*)(ws + TBL_OFF))[ri * 8 + h];
    float sg = 1.f / (1.f + expf(-bv));
    float sch = ((const float*)(ws + SC_OFF))[h];
    // +14.0: scale all e by 2^14 so the f16-rounded P stays in normal range
    // (raw e_max ~ 2^-20 is f16-subnormal -> 3% quantization; the 2^14 factor
    //  cancels exactly in O * 1/rowsum since rowsum uses the same scaled e).
    float val = (16.f * sg - sch - 16.f) * L2E + 14.0f;
    // permuted layout [h][mi][nj][c][g][r] for coalesced f32x4-over-r loads
    int mi = i >> 4, g = (i >> 2) & 3, r = i & 3;
    int nj = j >> 4, c = j & 15;
    int off = h * 4096 + mi * 1024 + nj * 256 + c * 16 + g * 4 + r;
    ((float*)(ws + BB_OFF))[off] = val;
}

// ---------------- fused main kernel ----------------
// 1 block = 1 window, 512 threads = 8 waves; wave w owns head w end-to-end.
// LDS (73728 B total -> 2 blocks/CU):
//   [0, 32768)      : x f16 [64][256] swz -> O f16 [64][256] swz -> f32 out staging [64][256]
//   [32768, 73728)  : per-wave 5120 B scratch (seq: V^T[32][72f16 pad] -> Qhat[64][40] -> Khat -> Phat halves)
// waves_per_eu(4,4): cap occupancy at 4 waves/EU (2 blocks/CU) so the
// allocator targets the 128-VGPR bucket instead of squeezing to 64 + spills
// (R3: VGPR=64 caused ~2.6 GB of scratch spill traffic -> HBM-bound at 3.7 GB).
#define SWZ(row) (((row) & 7) << 4)
#define LGKM0() asm volatile("s_waitcnt lgkmcnt(0)" ::: "memory")

__global__ __launch_bounds__(512) __attribute__((amdgpu_waves_per_eu(4, 4)))
void swin_fused(const float* __restrict__ x, const f16* __restrict__ wq,
                const f16* __restrict__ pw, const float* __restrict__ qb,
                const float* __restrict__ sc, const float* __restrict__ bb2,
                const float* __restrict__ pb, float* __restrict__ out) {
    extern __shared__ char lds[];
    const int tid = threadIdx.x;
    const int lane = tid & 63;
    const int w = tid >> 6;
    const int g = lane >> 4;
    const int c = lane & 15;
    const int win = blockIdx.x;
    char* scr = lds + 32768 + w * 5120;

    // ---- phase 0: stage x -> LDS fp16 (swizzled) ----
    const float* xw = x + (size_t)win * 16384;
    #pragma unroll
    for (int it = 0; it < 8; ++it) {
        int e4 = tid + it * 512;
        float4 v = ((const float4*)xw)[e4];
        int eidx = e4 * 4;
        int row = eidx >> 8, col = eidx & 255;
        f16x4 h4 = {(f16)v.x, (f16)v.y, (f16)v.z, (f16)v.w};
        int off = ((row << 9) + (col << 1)) ^ SWZ(row);
        *(f16x4*)(lds + off) = h4;
    }
    __syncthreads(); // (1)

    // ---- V GEMM (head w, cols 512+32w..+32), pack, V^T scratch, preload PV B-frags ----
    f16x8 vf[2][2]; // [dt][kt]
    {
        f32x4 acc[2][4] = {};
        for (int kk = 0; kk < 8; ++kk) {
            int kb = kk * 32 + g * 8;
            f16x8 a[4];
            #pragma unroll
            for (int mi = 0; mi < 4; ++mi) {
                int row = mi * 16 + c;
                int off = ((row << 9) + (kb << 1)) ^ SWZ(row);
                a[mi] = *(const f16x8*)(lds + off);
            }
            #pragma unroll
            for (int t = 0; t < 2; ++t) {
                f16x8 b = *(const f16x8*)(wq + (size_t)(512 + w * 32 + t * 16 + c) * 256 + kb);
                #pragma unroll
                for (int mi = 0; mi < 4; ++mi)
                    acc[t][mi] = __builtin_amdgcn_mfma_f32_16x16x32_f16(a[mi], b, acc[t][mi], 0, 0, 0);
            }
        }
        #pragma unroll
        for (int t = 0; t < 2; ++t) {
            float bias = qb[512 + w * 32 + t * 16 + c];
            #pragma unroll
            for (int mi = 0; mi < 4; ++mi) {
                f16x4 h;
                #pragma unroll
                for (int r = 0; r < 4; ++r) h[r] = (f16)(acc[t][mi][r] + bias);
                // V^T [d=32][token=64], row stride 144 B
                int off = (t * 16 + c) * 144 + (mi * 16 + g * 4) * 2;
                *(f16x4*)(scr + off) = h;
            }
        }
    }
    LGKM0();
    #pragma unroll
    for (int dt = 0; dt < 2; ++dt)
        #pragma unroll
        for (int kt = 0; kt < 2; ++kt)
            vf[dt][kt] = *(const f16x8*)(scr + (dt * 16 + c) * 144 + kt * 64 + g * 16);
    LGKM0();

    // ---- Q GEMM pass (head w, cols 32w..32w+32), normalize, pack via scratch ----
    // (split from K pass to flatten the register peak: R3's fused Q+K pass
    //  needed ~125 live VGPRs and spilled at the 64-reg allocation)
    f16x8 qf[4], kf[4];
    {
        f32x4 aq[2][4] = {};
        for (int kk = 0; kk < 8; ++kk) {
            int kb = kk * 32 + g * 8;
            f16x8 a[4];
            #pragma unroll
            for (int mi = 0; mi < 4; ++mi) {
                int row = mi * 16 + c;
                int off = ((row << 9) + (kb << 1)) ^ SWZ(row);
                a[mi] = *(const f16x8*)(lds + off);
            }
            #pragma unroll
            for (int t = 0; t < 2; ++t) {
                f16x8 bq = *(const f16x8*)(wq + (size_t)(w * 32 + t * 16 + c) * 256 + kb);
                #pragma unroll
                for (int mi = 0; mi < 4; ++mi)
                    aq[t][mi] = __builtin_amdgcn_mfma_f32_16x16x32_f16(a[mi], bq, aq[t][mi], 0, 0, 0);
            }
        }
        #pragma unroll
        for (int t = 0; t < 2; ++t) {
            float bias = qb[w * 32 + t * 16 + c];
            #pragma unroll
            for (int mi = 0; mi < 4; ++mi)
                #pragma unroll
                for (int r = 0; r < 4; ++r) aq[t][mi][r] += bias;
        }
        f32x4 rq[4];
        #pragma unroll
        for (int mi = 0; mi < 4; ++mi) {
            #pragma unroll
            for (int r = 0; r < 4; ++r) {
                float pq = aq[0][mi][r] * aq[0][mi][r] + aq[1][mi][r] * aq[1][mi][r];
                pq += __shfl_xor(pq, 1); pq += __shfl_xor(pq, 2);
                pq += __shfl_xor(pq, 4); pq += __shfl_xor(pq, 8);
                rq[mi][r] = __builtin_amdgcn_rsqf(fmaxf(pq, 1e-24f));
            }
        }
        // Qhat [token][d=32], row stride 80 B; scalar b16 writes, b128 frag reads
        #pragma unroll
        for (int t = 0; t < 2; ++t)
            #pragma unroll
            for (int mi = 0; mi < 4; ++mi)
                #pragma unroll
                for (int r = 0; r < 4; ++r) {
                    int off = (mi * 16 + g * 4 + r) * 80 + (t * 16 + c) * 2;
                    *(f16*)(scr + off) = (f16)(aq[t][mi][r] * rq[mi][r]);
                }
        LGKM0();
        #pragma unroll
        for (int mi = 0; mi < 4; ++mi)
            qf[mi] = *(const f16x8*)(scr + (mi * 16 + c) * 80 + g * 16);
        LGKM0();
    }
    // ---- K GEMM pass, same pattern (k bias is zero) ----
    {
        f32x4 ak[2][4] = {};
        for (int kk = 0; kk < 8; ++kk) {
            int kb = kk * 32 + g * 8;
            f16x8 a[4];
            #pragma unroll
            for (int mi = 0; mi < 4; ++mi) {
                int row = mi * 16 + c;
                int off = ((row << 9) + (kb << 1)) ^ SWZ(row);
                a[mi] = *(const f16x8*)(lds + off);
            }
            #pragma unroll
            for (int t = 0; t < 2; ++t) {
                f16x8 bk = *(const f16x8*)(wq + (size_t)(256 + w * 32 + t * 16 + c) * 256 + kb);
                #pragma unroll
                for (int mi = 0; mi < 4; ++mi)
                    ak[t][mi] = __builtin_amdgcn_mfma_f32_16x16x32_f16(a[mi], bk, ak[t][mi], 0, 0, 0);
            }
        }
        f32x4 rk[4];
        #pragma unroll
        for (int mi = 0; mi < 4; ++mi) {
            #pragma unroll
            for (int r = 0; r < 4; ++r) {
                float pk = ak[0][mi][r] * ak[0][mi][r] + ak[1][mi][r] * ak[1][mi][r];
                pk += __shfl_xor(pk, 1); pk += __shfl_xor(pk, 2);
                pk += __shfl_xor(pk, 4); pk += __shfl_xor(pk, 8);
                rk[mi][r] = __builtin_amdgcn_rsqf(fmaxf(pk, 1e-24f));
            }
        }
        #pragma unroll
        for (int t = 0; t < 2; ++t)
            #pragma unroll
            for (int mi = 0; mi < 4; ++mi)
                #pragma unroll
                for (int r = 0; r < 4; ++r) {
                    int off = (mi * 16 + g * 4 + r) * 80 + (t * 16 + c) * 2;
                    *(f16*)(scr + off) = (f16)(ak[t][mi][r] * rk[mi][r]);
                }
        LGKM0();
        #pragma unroll
        for (int nj = 0; nj < 4; ++nj)
            kf[nj] = *(const f16x8*)(scr + (nj * 16 + c) * 80 + g * 16);
        LGKM0();
    }

    // ---- QK quarters -> exp -> Phat halves in scratch, interleaved with PV K-steps ----
    const float scl2e = sc[w] * L2E;
    const float* bbw = bb2 + w * 4096;
    f32x4 o[4][2] = {};   // [mi_o][dt]
    f32x4 rs[4] = {};     // rowsum partials per (mi, r)
    #pragma unroll
    for (int nj = 0; nj < 4; ++nj) {
        #pragma unroll
        for (int mi = 0; mi < 4; ++mi) {
            f32x4 z = {};
            f32x4 s = __builtin_amdgcn_mfma_f32_16x16x32_f16(qf[mi], kf[nj], z, 0, 0, 0);
            f32x4 bb4 = *(const f32x4*)(bbw + mi * 1024 + nj * 256 + c * 16 + g * 4);
            #pragma unroll
            for (int r = 0; r < 4; ++r) {
                float e = exp2f(fmaf(s[r], scl2e, bb4[r]));
                rs[mi][r] += e;
                int off = (mi * 16 + g * 4 + r) * 80 + (((nj & 1) * 16 + c) << 1);
                *(f16*)(scr + off) = (f16)e;
            }
        }
        if (nj == 1 || nj == 3) {
            const int kt = nj >> 1;
            LGKM0();
            f16x8 pa[4];
            #pragma unroll
            for (int mo = 0; mo < 4; ++mo)
                pa[mo] = *(const f16x8*)(scr + (mo * 16 + c) * 80 + g * 16);
            LGKM0();
            #pragma unroll
            for (int mo = 0; mo < 4; ++mo)
                #pragma unroll
                for (int dt = 0; dt < 2; ++dt)
                    o[mo][dt] = __builtin_amdgcn_mfma_f32_16x16x32_f16(pa[mo], vf[dt][kt], o[mo][dt], 0, 0, 0);
        }
    }
    // rowsum reduce + reciprocal (2^14 scale cancels here: o and rs share it)
    f32x4 rinv[4];
    #pragma unroll
    for (int mi = 0; mi < 4; ++mi)
        #pragma unroll
        for (int r = 0; r < 4; ++r) {
            float t = rs[mi][r];
            t += __shfl_xor(t, 1); t += __shfl_xor(t, 2);
            t += __shfl_xor(t, 4); t += __shfl_xor(t, 8);
            rinv[mi][r] = __builtin_amdgcn_rcpf(t);
        }

    __syncthreads(); // (2) all waves done reading x region -> O may overwrite
    #pragma unroll
    for (int mi = 0; mi < 4; ++mi)
        #pragma unroll
        for (int dt = 0; dt < 2; ++dt)
            #pragma unroll
            for (int r = 0; r < 4; ++r) {
                int row = mi * 16 + g * 4 + r;
                int col = w * 32 + dt * 16 + c;
                int off = ((row << 9) + (col << 1)) ^ SWZ(row);
                *(f16*)(lds + off) = (f16)(o[mi][dt][r] * rinv[mi][r]);
            }
    __syncthreads(); // (3) O complete -> proj may read

    // ---- proj GEMM: wave w -> out cols [32w, 32w+32) ----
    f32x4 pacc[2][4] = {};
    for (int kk = 0; kk < 8; ++kk) {
        int kb = kk * 32 + g * 8;
        f16x8 a[4];
        #pragma unroll
        for (int mi = 0; mi < 4; ++mi) {
            int row = mi * 16 + c;
            int off = ((row << 9) + (kb << 1)) ^ SWZ(row);
            a[mi] = *(const f16x8*)(lds + off);
        }
        #pragma unroll
        for (int nt = 0; nt < 2; ++nt) {
            f16x8 b = *(const f16x8*)(pw + (size_t)(w * 32 + nt * 16 + c) * 256 + kb);
            #pragma unroll
            for (int mi = 0; mi < 4; ++mi)
                pacc[nt][mi] = __builtin_amdgcn_mfma_f32_16x16x32_f16(a[mi], b, pacc[nt][mi], 0, 0, 0);
        }
    }
    __syncthreads(); // (4) all LDS dead -> f32 staging may overwrite everything

    // ---- stage f32 output in LDS, then full-line float4 global writes ----
    #pragma unroll
    for (int nt = 0; nt < 2; ++nt) {
        float pbias = pb[w * 32 + nt * 16 + c];
        #pragma unroll
        for (int mi = 0; mi < 4; ++mi)
            #pragma unroll
            for (int r = 0; r < 4; ++r) {
                int row = mi * 16 + g * 4 + r;
                int col = w * 32 + nt * 16 + c;
                int off = (row * 1024 + col * 4) ^ ((row & 7) << 4);
                *(float*)(lds + off) = pacc[nt][mi][r] + pbias;
            }
    }
    __syncthreads(); // (5)
    float4* out4 = (float4*)(out + (size_t)win * 16384);
    #pragma unroll
    for (int it = 0; it < 8; ++it) {
        int e4 = it * 512 + tid;
        int off = (e4 * 16) ^ (((e4 >> 6) & 7) << 4);
        out4[e4] = *(const float4*)(lds + off);
    }
}

// ---------------- launch ----------------

extern "C" void kernel_launch(void* const* d_in, const int* in_sizes, int n_in,
                              void* d_out, int out_size, void* d_ws, size_t ws_size,
                              hipStream_t stream) {
    (void)in_sizes; (void)n_in; (void)out_size; (void)ws_size;
    const float* x   = (const float*)d_in[0];
    const float* qw  = (const float*)d_in[1];
    const float* qb_ = (const float*)d_in[2];
    const float* vb_ = (const float*)d_in[3];
    const float* ls  = (const float*)d_in[4];
    const float* w1  = (const float*)d_in[5];
    const float* b1  = (const float*)d_in[6];
    const float* w2  = (const float*)d_in[7];
    const float* prw = (const float*)d_in[8];
    const float* pb  = (const float*)d_in[9];
    float* out = (float*)d_out;
    char* ws = (char*)d_ws;

    prep0<<<1024, 256, 0, stream>>>(qw, prw, qb_, vb_, ls, ws);
    prep1<<<8, 256, 0, stream>>>(w1, b1, w2, ws);
    prep2<<<128, 256, 0, stream>>>(ws);

    (void)hipFuncSetAttribute((const void*)swin_fused,
                              hipFuncAttributeMaxDynamicSharedMemorySize, 73728);
    swin_fused<<<8192, 512, 73728, stream>>>(
        x,
        (const f16*)(ws + WQ_OFF), (const f16*)(ws + PW_OFF),
        (const float*)(ws + QB_OFF), (const float*)(ws + SC_OFF),
        (const float*)(ws + BB_OFF), pb, out);
}

// Round 5
// 944.601 us; speedup vs baseline: 1.4677x; 1.4677x over previous
//
#include <hip/hip_runtime.h>
#include <hip/hip_fp16.h>

typedef _Float16 f16;
typedef _Float16 f16x8 __attribute__((ext_vector_type(8)));
typedef _Float16 f16x4 __attribute__((ext_vector_type(4)));
typedef float f32x4 __attribute__((ext_vector_type(4)));

#define L2E 1.4426950408889634f

// workspace layout (bytes)
#define WQ_OFF   0         // 768*256 f16   qkv weight, row-major [n][k]
#define PW_OFF   393216    // 256*256 f16   proj weight, row-major [n][k]
#define QB_OFF   524288    // 768 f32       concat qkv bias (k-bias = 0)
#define SC_OFF   527360    // 8 f32         exp(min(logit_scale, ln100))
#define TBL_OFF  527616    // 225*8 f32     cpb mlp table
#define BB_OFF   535040    // 32768 f32     folded bias, permuted [h][mi][nj][c][g][r]

// ---------------- prep kernels ----------------

__global__ void prep0(const float* __restrict__ qw, const float* __restrict__ prw,
                      const float* __restrict__ qbias, const float* __restrict__ vbias,
                      const float* __restrict__ ls, char* __restrict__ ws) {
    int t = blockIdx.x * 256 + threadIdx.x;
    f16* wq = (f16*)(ws + WQ_OFF);
    f16* pw = (f16*)(ws + PW_OFF);
    if (t < 196608) wq[t] = (f16)qw[t];
    else            pw[t - 196608] = (f16)prw[t - 196608];
    if (t < 768) {
        float b = t < 256 ? qbias[t] : (t < 512 ? 0.f : vbias[t - 512]);
        ((float*)(ws + QB_OFF))[t] = b;
    }
    if (t < 8) ((float*)(ws + SC_OFF))[t] = expf(fminf(ls[t], 4.6051701859880914f));
}

__device__ __forceinline__ float norm_coord(int u) { // u in 0..14
    float v = (float)(u - 7) * (8.0f / 7.0f);
    float s = (v > 0.f) ? 1.f : ((v < 0.f) ? -1.f : 0.f);
    return s * log2f(fabsf(v) + 1.f) * (1.f / 3.f);
}

__global__ void prep1(const float* __restrict__ w1, const float* __restrict__ b1,
                      const float* __restrict__ w2, char* __restrict__ ws) {
    int t = blockIdx.x * 256 + threadIdx.x; // 1800 used
    if (t >= 1800) return;
    int p = t >> 3, h = t & 7;
    float ta = norm_coord(p / 15);
    float tb = norm_coord(p % 15);
    float acc = 0.f;
    for (int j = 0; j < 512; ++j) {
        float hv = fmaf(w1[2 * j], ta, fmaf(w1[2 * j + 1], tb, b1[j]));
        acc = fmaf(fmaxf(hv, 0.f), w2[h * 512 + j], acc);
    }
    ((float*)(ws + TBL_OFF))[p * 8 + h] = acc;
}

__global__ void prep2(char* __restrict__ ws) {
    int t = blockIdx.x * 256 + threadIdx.x; // 32768 = 8*64*64
    int h = t >> 12, i = (t >> 6) & 63, j = t & 63;
    int ri = ((i >> 3) - (j >> 3) + 7) * 15 + ((i & 7) - (j & 7) + 7);
    float bv = ((const float*)(ws + TBL_OFF))[ri * 8 + h];
    float sg = 1.f / (1.f + expf(-bv));
    float sch = ((const float*)(ws + SC_OFF))[h];
    // +14.0: scale all e by 2^14 so the f16-rounded P stays in normal range
    // (raw e_max ~ 2^-20 is f16-subnormal -> 3% quantization; the 2^14 factor
    //  cancels exactly in O * 1/rowsum since rowsum uses the same scaled e).
    float val = (16.f * sg - sch - 16.f) * L2E + 14.0f;
    // permuted layout [h][mi][nj][c][g][r] for coalesced f32x4-over-r loads
    int mi = i >> 4, g = (i >> 2) & 3, r = i & 3;
    int nj = j >> 4, c = j & 15;
    int off = h * 4096 + mi * 1024 + nj * 256 + c * 16 + g * 4 + r;
    ((float*)(ws + BB_OFF))[off] = val;
}

// ---------------- fused main kernel ----------------
// 1 block = 1 window, 512 threads = 8 waves; wave w owns head w end-to-end.
// LDS (73728 B total -> 2 blocks/CU):
//   [0, 32768)      : x f16 [64][256] swz -> O f16 [64][256] swz -> f32 out staging [64][256]
//   [32768, 73728)  : per-wave 5120 B scratch (seq: V^T[32][72f16 pad] -> Qhat[64][40] -> Khat -> Phat halves)
// __launch_bounds__(512, 2): min 2 waves/EU -> VGPR cap 256. Empirically (R1)
// this yields a spill-free allocation; every attempt to request >=4 waves/EU
// (R3 (512,4), R4 wpe(4,4)) pinned the allocator to 64 VGPR and generated
// 2.5-3.5 GB of scratch spill traffic -> HBM-bound at ~3.2 TB/s.
#define SWZ(row) (((row) & 7) << 4)
#define LGKM0() asm volatile("s_waitcnt lgkmcnt(0)" ::: "memory")

__global__ __launch_bounds__(512, 2)
void swin_fused(const float* __restrict__ x, const f16* __restrict__ wq,
                const f16* __restrict__ pw, const float* __restrict__ qb,
                const float* __restrict__ sc, const float* __restrict__ bb2,
                const float* __restrict__ pb, float* __restrict__ out) {
    extern __shared__ char lds[];
    const int tid = threadIdx.x;
    const int lane = tid & 63;
    const int w = tid >> 6;
    const int g = lane >> 4;
    const int c = lane & 15;
    const int win = blockIdx.x;
    char* scr = lds + 32768 + w * 5120;

    // ---- phase 0: stage x -> LDS fp16 (swizzled) ----
    const float* xw = x + (size_t)win * 16384;
    #pragma unroll
    for (int it = 0; it < 8; ++it) {
        int e4 = tid + it * 512;
        float4 v = ((const float4*)xw)[e4];
        int eidx = e4 * 4;
        int row = eidx >> 8, col = eidx & 255;
        f16x4 h4 = {(f16)v.x, (f16)v.y, (f16)v.z, (f16)v.w};
        int off = ((row << 9) + (col << 1)) ^ SWZ(row);
        *(f16x4*)(lds + off) = h4;
    }
    __syncthreads(); // (1)

    // ---- V GEMM (head w, cols 512+32w..+32), pack, V^T scratch, preload PV B-frags ----
    f16x8 vf[2][2]; // [dt][kt]
    {
        f32x4 acc[2][4] = {};
        for (int kk = 0; kk < 8; ++kk) {
            int kb = kk * 32 + g * 8;
            f16x8 a[4];
            #pragma unroll
            for (int mi = 0; mi < 4; ++mi) {
                int row = mi * 16 + c;
                int off = ((row << 9) + (kb << 1)) ^ SWZ(row);
                a[mi] = *(const f16x8*)(lds + off);
            }
            #pragma unroll
            for (int t = 0; t < 2; ++t) {
                f16x8 b = *(const f16x8*)(wq + (size_t)(512 + w * 32 + t * 16 + c) * 256 + kb);
                #pragma unroll
                for (int mi = 0; mi < 4; ++mi)
                    acc[t][mi] = __builtin_amdgcn_mfma_f32_16x16x32_f16(a[mi], b, acc[t][mi], 0, 0, 0);
            }
        }
        #pragma unroll
        for (int t = 0; t < 2; ++t) {
            float bias = qb[512 + w * 32 + t * 16 + c];
            #pragma unroll
            for (int mi = 0; mi < 4; ++mi) {
                f16x4 h;
                #pragma unroll
                for (int r = 0; r < 4; ++r) h[r] = (f16)(acc[t][mi][r] + bias);
                // V^T [d=32][token=64], row stride 144 B
                int off = (t * 16 + c) * 144 + (mi * 16 + g * 4) * 2;
                *(f16x4*)(scr + off) = h;
            }
        }
    }
    LGKM0();
    #pragma unroll
    for (int dt = 0; dt < 2; ++dt)
        #pragma unroll
        for (int kt = 0; kt < 2; ++kt)
            vf[dt][kt] = *(const f16x8*)(scr + (dt * 16 + c) * 144 + kt * 64 + g * 16);
    LGKM0();

    // ---- Q GEMM pass (head w, cols 32w..32w+32), normalize, pack via scratch ----
    // (split from K pass to flatten the register peak)
    f16x8 qf[4], kf[4];
    {
        f32x4 aq[2][4] = {};
        for (int kk = 0; kk < 8; ++kk) {
            int kb = kk * 32 + g * 8;
            f16x8 a[4];
            #pragma unroll
            for (int mi = 0; mi < 4; ++mi) {
                int row = mi * 16 + c;
                int off = ((row << 9) + (kb << 1)) ^ SWZ(row);
                a[mi] = *(const f16x8*)(lds + off);
            }
            #pragma unroll
            for (int t = 0; t < 2; ++t) {
                f16x8 bq = *(const f16x8*)(wq + (size_t)(w * 32 + t * 16 + c) * 256 + kb);
                #pragma unroll
                for (int mi = 0; mi < 4; ++mi)
                    aq[t][mi] = __builtin_amdgcn_mfma_f32_16x16x32_f16(a[mi], bq, aq[t][mi], 0, 0, 0);
            }
        }
        #pragma unroll
        for (int t = 0; t < 2; ++t) {
            float bias = qb[w * 32 + t * 16 + c];
            #pragma unroll
            for (int mi = 0; mi < 4; ++mi)
                #pragma unroll
                for (int r = 0; r < 4; ++r) aq[t][mi][r] += bias;
        }
        f32x4 rq[4];
        #pragma unroll
        for (int mi = 0; mi < 4; ++mi) {
            #pragma unroll
            for (int r = 0; r < 4; ++r) {
                float pq = aq[0][mi][r] * aq[0][mi][r] + aq[1][mi][r] * aq[1][mi][r];
                pq += __shfl_xor(pq, 1); pq += __shfl_xor(pq, 2);
                pq += __shfl_xor(pq, 4); pq += __shfl_xor(pq, 8);
                rq[mi][r] = __builtin_amdgcn_rsqf(fmaxf(pq, 1e-24f));
            }
        }
        // Qhat [token][d=32], row stride 80 B; scalar b16 writes, b128 frag reads
        #pragma unroll
        for (int t = 0; t < 2; ++t)
            #pragma unroll
            for (int mi = 0; mi < 4; ++mi)
                #pragma unroll
                for (int r = 0; r < 4; ++r) {
                    int off = (mi * 16 + g * 4 + r) * 80 + (t * 16 + c) * 2;
                    *(f16*)(scr + off) = (f16)(aq[t][mi][r] * rq[mi][r]);
                }
        LGKM0();
        #pragma unroll
        for (int mi = 0; mi < 4; ++mi)
            qf[mi] = *(const f16x8*)(scr + (mi * 16 + c) * 80 + g * 16);
        LGKM0();
    }
    // ---- K GEMM pass, same pattern (k bias is zero) ----
    {
        f32x4 ak[2][4] = {};
        for (int kk = 0; kk < 8; ++kk) {
            int kb = kk * 32 + g * 8;
            f16x8 a[4];
            #pragma unroll
            for (int mi = 0; mi < 4; ++mi) {
                int row = mi * 16 + c;
                int off = ((row << 9) + (kb << 1)) ^ SWZ(row);
                a[mi] = *(const f16x8*)(lds + off);
            }
            #pragma unroll
            for (int t = 0; t < 2; ++t) {
                f16x8 bk = *(const f16x8*)(wq + (size_t)(256 + w * 32 + t * 16 + c) * 256 + kb);
                #pragma unroll
                for (int mi = 0; mi < 4; ++mi)
                    ak[t][mi] = __builtin_amdgcn_mfma_f32_16x16x32_f16(a[mi], bk, ak[t][mi], 0, 0, 0);
            }
        }
        f32x4 rk[4];
        #pragma unroll
        for (int mi = 0; mi < 4; ++mi) {
            #pragma unroll
            for (int r = 0; r < 4; ++r) {
                float pk = ak[0][mi][r] * ak[0][mi][r] + ak[1][mi][r] * ak[1][mi][r];
                pk += __shfl_xor(pk, 1); pk += __shfl_xor(pk, 2);
                pk += __shfl_xor(pk, 4); pk += __shfl_xor(pk, 8);
                rk[mi][r] = __builtin_amdgcn_rsqf(fmaxf(pk, 1e-24f));
            }
        }
        #pragma unroll
        for (int t = 0; t < 2; ++t)
            #pragma unroll
            for (int mi = 0; mi < 4; ++mi)
                #pragma unroll
                for (int r = 0; r < 4; ++r) {
                    int off = (mi * 16 + g * 4 + r) * 80 + (t * 16 + c) * 2;
                    *(f16*)(scr + off) = (f16)(ak[t][mi][r] * rk[mi][r]);
                }
        LGKM0();
        #pragma unroll
        for (int nj = 0; nj < 4; ++nj)
            kf[nj] = *(const f16x8*)(scr + (nj * 16 + c) * 80 + g * 16);
        LGKM0();
    }

    // ---- QK quarters -> exp -> Phat halves in scratch, interleaved with PV K-steps ----
    const float scl2e = sc[w] * L2E;
    const float* bbw = bb2 + w * 4096;
    f32x4 o[4][2] = {};   // [mi_o][dt]
    f32x4 rs[4] = {};     // rowsum partials per (mi, r)
    #pragma unroll
    for (int nj = 0; nj < 4; ++nj) {
        #pragma unroll
        for (int mi = 0; mi < 4; ++mi) {
            f32x4 z = {};
            f32x4 s = __builtin_amdgcn_mfma_f32_16x16x32_f16(qf[mi], kf[nj], z, 0, 0, 0);
            f32x4 bb4 = *(const f32x4*)(bbw + mi * 1024 + nj * 256 + c * 16 + g * 4);
            #pragma unroll
            for (int r = 0; r < 4; ++r) {
                float e = exp2f(fmaf(s[r], scl2e, bb4[r]));
                rs[mi][r] += e;
                int off = (mi * 16 + g * 4 + r) * 80 + (((nj & 1) * 16 + c) << 1);
                *(f16*)(scr + off) = (f16)e;
            }
        }
        if (nj == 1 || nj == 3) {
            const int kt = nj >> 1;
            LGKM0();
            f16x8 pa[4];
            #pragma unroll
            for (int mo = 0; mo < 4; ++mo)
                pa[mo] = *(const f16x8*)(scr + (mo * 16 + c) * 80 + g * 16);
            LGKM0();
            #pragma unroll
            for (int mo = 0; mo < 4; ++mo)
                #pragma unroll
                for (int dt = 0; dt < 2; ++dt)
                    o[mo][dt] = __builtin_amdgcn_mfma_f32_16x16x32_f16(pa[mo], vf[dt][kt], o[mo][dt], 0, 0, 0);
        }
    }
    // rowsum reduce + reciprocal (2^14 scale cancels here: o and rs share it)
    f32x4 rinv[4];
    #pragma unroll
    for (int mi = 0; mi < 4; ++mi)
        #pragma unroll
        for (int r = 0; r < 4; ++r) {
            float t = rs[mi][r];
            t += __shfl_xor(t, 1); t += __shfl_xor(t, 2);
            t += __shfl_xor(t, 4); t += __shfl_xor(t, 8);
            rinv[mi][r] = __builtin_amdgcn_rcpf(t);
        }

    __syncthreads(); // (2) all waves done reading x region -> O may overwrite
    #pragma unroll
    for (int mi = 0; mi < 4; ++mi)
        #pragma unroll
        for (int dt = 0; dt < 2; ++dt)
            #pragma unroll
            for (int r = 0; r < 4; ++r) {
                int row = mi * 16 + g * 4 + r;
                int col = w * 32 + dt * 16 + c;
                int off = ((row << 9) + (col << 1)) ^ SWZ(row);
                *(f16*)(lds + off) = (f16)(o[mi][dt][r] * rinv[mi][r]);
            }
    __syncthreads(); // (3) O complete -> proj may read

    // ---- proj GEMM: wave w -> out cols [32w, 32w+32) ----
    f32x4 pacc[2][4] = {};
    for (int kk = 0; kk < 8; ++kk) {
        int kb = kk * 32 + g * 8;
        f16x8 a[4];
        #pragma unroll
        for (int mi = 0; mi < 4; ++mi) {
            int row = mi * 16 + c;
            int off = ((row << 9) + (kb << 1)) ^ SWZ(row);
            a[mi] = *(const f16x8*)(lds + off);
        }
        #pragma unroll
        for (int nt = 0; nt < 2; ++nt) {
            f16x8 b = *(const f16x8*)(pw + (size_t)(w * 32 + nt * 16 + c) * 256 + kb);
            #pragma unroll
            for (int mi = 0; mi < 4; ++mi)
                pacc[nt][mi] = __builtin_amdgcn_mfma_f32_16x16x32_f16(a[mi], b, pacc[nt][mi], 0, 0, 0);
        }
    }
    __syncthreads(); // (4) all LDS dead -> f32 staging may overwrite everything

    // ---- stage f32 output in LDS, then full-line float4 global writes ----
    #pragma unroll
    for (int nt = 0; nt < 2; ++nt) {
        float pbias = pb[w * 32 + nt * 16 + c];
        #pragma unroll
        for (int mi = 0; mi < 4; ++mi)
            #pragma unroll
            for (int r = 0; r < 4; ++r) {
                int row = mi * 16 + g * 4 + r;
                int col = w * 32 + nt * 16 + c;
                int off = (row * 1024 + col * 4) ^ ((row & 7) << 4);
                *(float*)(lds + off) = pacc[nt][mi][r] + pbias;
            }
    }
    __syncthreads(); // (5)
    float4* out4 = (float4*)(out + (size_t)win * 16384);
    #pragma unroll
    for (int it = 0; it < 8; ++it) {
        int e4 = it * 512 + tid;
        int off = (e4 * 16) ^ (((e4 >> 6) & 7) << 4);
        out4[e4] = *(const float4*)(lds + off);
    }
}

// ---------------- launch ----------------

extern "C" void kernel_launch(void* const* d_in, const int* in_sizes, int n_in,
                              void* d_out, int out_size, void* d_ws, size_t ws_size,
                              hipStream_t stream) {
    (void)in_sizes; (void)n_in; (void)out_size; (void)ws_size;
    const float* x   = (const float*)d_in[0];
    const float* qw  = (const float*)d_in[1];
    const float* qb_ = (const float*)d_in[2];
    const float* vb_ = (const float*)d_in[3];
    const float* ls  = (const float*)d_in[4];
    const float* w1  = (const float*)d_in[5];
    const float* b1  = (const float*)d_in[6];
    const float* w2  = (const float*)d_in[7];
    const float* prw = (const float*)d_in[8];
    const float* pb  = (const float*)d_in[9];
    float* out = (float*)d_out;
    char* ws = (char*)d_ws;

    prep0<<<1024, 256, 0, stream>>>(qw, prw, qb_, vb_, ls, ws);
    prep1<<<8, 256, 0, stream>>>(w1, b1, w2, ws);
    prep2<<<128, 256, 0, stream>>>(ws);

    (void)hipFuncSetAttribute((const void*)swin_fused,
                              hipFuncAttributeMaxDynamicSharedMemorySize, 73728);
    swin_fused<<<8192, 512, 73728, stream>>>(
        x,
        (const f16*)(ws + WQ_OFF), (const f16*)(ws + PW_OFF),
        (const float*)(ws + QB_OFF), (const float*)(ws + SC_OFF),
        (const float*)(ws + BB_OFF), pb, out);
}

// Round 6
// 771.985 us; speedup vs baseline: 1.7959x; 1.2236x over previous
//
#include <hip/hip_runtime.h>
#include <hip/hip_fp16.h>

typedef _Float16 f16;
typedef _Float16 f16x8 __attribute__((ext_vector_type(8)));
typedef _Float16 f16x4 __attribute__((ext_vector_type(4)));
typedef float f32x4 __attribute__((ext_vector_type(4)));

#define L2E 1.4426950408889634f

// workspace layout (bytes)
#define WQ_OFF   0         // 768*256 f16   qkv weight, row-major [n][k]
#define PW_OFF   393216    // 256*256 f16   proj weight, row-major [n][k]
#define QB_OFF   524288    // 768 f32       concat qkv bias (k-bias = 0)
#define SC_OFF   527360    // 8 f32         exp(min(logit_scale, ln100))
#define TBL_OFF  527616    // 225*8 f32     cpb mlp table
#define BB_OFF   535040    // 32768 f32     folded bias, permuted [h][mi][nj][c][g][r]

// ---------------- prep kernels ----------------

__global__ void prep0(const float* __restrict__ qw, const float* __restrict__ prw,
                      const float* __restrict__ qbias, const float* __restrict__ vbias,
                      const float* __restrict__ ls, char* __restrict__ ws) {
    int t = blockIdx.x * 256 + threadIdx.x;
    f16* wq = (f16*)(ws + WQ_OFF);
    f16* pw = (f16*)(ws + PW_OFF);
    if (t < 196608) wq[t] = (f16)qw[t];
    else            pw[t - 196608] = (f16)prw[t - 196608];
    if (t < 768) {
        float b = t < 256 ? qbias[t] : (t < 512 ? 0.f : vbias[t - 512]);
        ((float*)(ws + QB_OFF))[t] = b;
    }
    if (t < 8) ((float*)(ws + SC_OFF))[t] = expf(fminf(ls[t], 4.6051701859880914f));
}

__device__ __forceinline__ float norm_coord(int u) { // u in 0..14
    float v = (float)(u - 7) * (8.0f / 7.0f);
    float s = (v > 0.f) ? 1.f : ((v < 0.f) ? -1.f : 0.f);
    return s * log2f(fabsf(v) + 1.f) * (1.f / 3.f);
}

__global__ void prep1(const float* __restrict__ w1, const float* __restrict__ b1,
                      const float* __restrict__ w2, char* __restrict__ ws) {
    int t = blockIdx.x * 256 + threadIdx.x; // 1800 used
    if (t >= 1800) return;
    int p = t >> 3, h = t & 7;
    float ta = norm_coord(p / 15);
    float tb = norm_coord(p % 15);
    float acc = 0.f;
    for (int j = 0; j < 512; ++j) {
        float hv = fmaf(w1[2 * j], ta, fmaf(w1[2 * j + 1], tb, b1[j]));
        acc = fmaf(fmaxf(hv, 0.f), w2[h * 512 + j], acc);
    }
    ((float*)(ws + TBL_OFF))[p * 8 + h] = acc;
}

__global__ void prep2(char* __restrict__ ws) {
    int t = blockIdx.x * 256 + threadIdx.x; // 32768 = 8*64*64
    int h = t >> 12, i = (t >> 6) & 63, j = t & 63;
    int ri = ((i >> 3) - (j >> 3) + 7) * 15 + ((i & 7) - (j & 7) + 7);
    float bv = ((const float*)(ws + TBL_OFF))[ri * 8 + h];
    float sg = 1.f / (1.f + expf(-bv));
    float sch = ((const float*)(ws + SC_OFF))[h];
    // +14.0: scale all e by 2^14 so the f16-rounded P stays in normal range;
    // the factor cancels exactly in O * 1/rowsum (rowsum uses the same scaled e).
    float val = (16.f * sg - sch - 16.f) * L2E + 14.0f;
    // permuted layout [h][mi][nj][c][g][r] for coalesced f32x4-over-r loads
    int mi = i >> 4, g = (i >> 2) & 3, r = i & 3;
    int nj = j >> 4, c = j & 15;
    int off = h * 4096 + mi * 1024 + nj * 256 + c * 16 + g * 4 + r;
    ((float*)(ws + BB_OFF))[off] = val;
}

// ---------------- fused main kernel ----------------
// 1 block = 1 window, 256 threads = 4 waves; wave w runs heads w and w+4.
// LDS (53248 B -> up to 3 blocks/CU):
//   [0, 32768)      : x f16 [64][256] swz -> O f16 (same region) -> f32 out staging (2 passes)
//   [32768, 53248)  : per-wave 5120 B scratch (seq per head: V^T -> Qhat -> Khat -> P)
// Occupancy model (R1..R5 evidence): pool=512 regs/SIMD, alloc = archVGPR + AGPR.
// R5: 116+64=180 -> 2 waves/SIMD. This design targets <=170 total (3 waves/SIMD
// = 12 waves/CU with 4-wave blocks); head-0 O carried as packed f16 regs,
// rowsum via ones-column MFMA (kills the rs[16] accumulator + 64 ds_swizzles).
#define SWZ(row) (((row) & 7) << 4)
#define LGKM0() asm volatile("s_waitcnt lgkmcnt(0)" ::: "memory")

__global__ __launch_bounds__(256, 2)
void swin_fused(const float* __restrict__ x, const f16* __restrict__ wq,
                const f16* __restrict__ pw, const float* __restrict__ qb,
                const float* __restrict__ sc, const float* __restrict__ bb2,
                const float* __restrict__ pb, float* __restrict__ out) {
    extern __shared__ char lds[];
    const int tid = threadIdx.x;      // 0..255
    const int lane = tid & 63;
    const int w = tid >> 6;           // wave 0..3
    const int g = lane >> 4;
    const int c = lane & 15;
    const int win = blockIdx.x;
    char* scr = lds + 32768 + w * 5120;

    // ---- phase 0: stage x -> LDS fp16 (swizzled) ----
    const float* xw = x + (size_t)win * 16384;
    #pragma unroll
    for (int it = 0; it < 16; ++it) {
        int e4 = tid + it * 256;
        float4 v = ((const float4*)xw)[e4];
        int eidx = e4 * 4;
        int row = eidx >> 8, col = eidx & 255;
        f16x4 h4 = {(f16)v.x, (f16)v.y, (f16)v.z, (f16)v.w};
        int off = ((row << 9) + (col << 1)) ^ SWZ(row);
        *(f16x4*)(lds + off) = h4;
    }
    __syncthreads(); // (1)

    f16x4 po[4][2]; // head-0 packed O (carried through head-1): [mi][dt] x 4 r-vals

    for (int hh = 0; hh < 2; ++hh) {
        const int h = w + hh * 4;

        // ---- V GEMM (head h, cols 512+32h..+32) -> V^T scratch -> vf regs ----
        f16x8 vf[2][2]; // [dt][kt]
        {
            f32x4 acc[2][4] = {};
            #pragma unroll 2
            for (int kk = 0; kk < 8; ++kk) {
                int kb = kk * 32 + g * 8;
                f16x8 a[4];
                #pragma unroll
                for (int mi = 0; mi < 4; ++mi) {
                    int row = mi * 16 + c;
                    int off = ((row << 9) + (kb << 1)) ^ SWZ(row);
                    a[mi] = *(const f16x8*)(lds + off);
                }
                #pragma unroll
                for (int t = 0; t < 2; ++t) {
                    f16x8 b = *(const f16x8*)(wq + (size_t)(512 + h * 32 + t * 16 + c) * 256 + kb);
                    #pragma unroll
                    for (int mi = 0; mi < 4; ++mi)
                        acc[t][mi] = __builtin_amdgcn_mfma_f32_16x16x32_f16(a[mi], b, acc[t][mi], 0, 0, 0);
                }
            }
            #pragma unroll
            for (int t = 0; t < 2; ++t) {
                float bias = qb[512 + h * 32 + t * 16 + c];
                #pragma unroll
                for (int mi = 0; mi < 4; ++mi) {
                    f16x4 hv;
                    #pragma unroll
                    for (int r = 0; r < 4; ++r) hv[r] = (f16)(acc[t][mi][r] + bias);
                    // V^T [d=32][token=64], row stride 144 B
                    int off = (t * 16 + c) * 144 + (mi * 16 + g * 4) * 2;
                    *(f16x4*)(scr + off) = hv;
                }
            }
        }
        LGKM0();
        #pragma unroll
        for (int dt = 0; dt < 2; ++dt)
            #pragma unroll
            for (int kt = 0; kt < 2; ++kt)
                vf[dt][kt] = *(const f16x8*)(scr + (dt * 16 + c) * 144 + kt * 64 + g * 16);
        LGKM0();

        // ---- Q GEMM pass -> normalize -> Qhat scratch -> qf regs ----
        f16x8 qf[4], kf[4];
        {
            f32x4 aq[2][4] = {};
            #pragma unroll 2
            for (int kk = 0; kk < 8; ++kk) {
                int kb = kk * 32 + g * 8;
                f16x8 a[4];
                #pragma unroll
                for (int mi = 0; mi < 4; ++mi) {
                    int row = mi * 16 + c;
                    int off = ((row << 9) + (kb << 1)) ^ SWZ(row);
                    a[mi] = *(const f16x8*)(lds + off);
                }
                #pragma unroll
                for (int t = 0; t < 2; ++t) {
                    f16x8 bq = *(const f16x8*)(wq + (size_t)(h * 32 + t * 16 + c) * 256 + kb);
                    #pragma unroll
                    for (int mi = 0; mi < 4; ++mi)
                        aq[t][mi] = __builtin_amdgcn_mfma_f32_16x16x32_f16(a[mi], bq, aq[t][mi], 0, 0, 0);
                }
            }
            #pragma unroll
            for (int t = 0; t < 2; ++t) {
                float bias = qb[h * 32 + t * 16 + c];
                #pragma unroll
                for (int mi = 0; mi < 4; ++mi)
                    #pragma unroll
                    for (int r = 0; r < 4; ++r) aq[t][mi][r] += bias;
            }
            #pragma unroll
            for (int mi = 0; mi < 4; ++mi) {
                #pragma unroll
                for (int r = 0; r < 4; ++r) {
                    float pq = aq[0][mi][r] * aq[0][mi][r] + aq[1][mi][r] * aq[1][mi][r];
                    pq += __shfl_xor(pq, 1); pq += __shfl_xor(pq, 2);
                    pq += __shfl_xor(pq, 4); pq += __shfl_xor(pq, 8);
                    float rq = __builtin_amdgcn_rsqf(fmaxf(pq, 1e-24f));
                    aq[0][mi][r] *= rq; aq[1][mi][r] *= rq;
                }
            }
            #pragma unroll
            for (int t = 0; t < 2; ++t)
                #pragma unroll
                for (int mi = 0; mi < 4; ++mi)
                    #pragma unroll
                    for (int r = 0; r < 4; ++r) {
                        int off = (mi * 16 + g * 4 + r) * 80 + (t * 16 + c) * 2;
                        *(f16*)(scr + off) = (f16)aq[t][mi][r];
                    }
            LGKM0();
            #pragma unroll
            for (int mi = 0; mi < 4; ++mi)
                qf[mi] = *(const f16x8*)(scr + (mi * 16 + c) * 80 + g * 16);
            LGKM0();
        }
        // ---- K GEMM pass (k bias zero) -> Khat -> kf regs ----
        {
            f32x4 ak[2][4] = {};
            #pragma unroll 2
            for (int kk = 0; kk < 8; ++kk) {
                int kb = kk * 32 + g * 8;
                f16x8 a[4];
                #pragma unroll
                for (int mi = 0; mi < 4; ++mi) {
                    int row = mi * 16 + c;
                    int off = ((row << 9) + (kb << 1)) ^ SWZ(row);
                    a[mi] = *(const f16x8*)(lds + off);
                }
                #pragma unroll
                for (int t = 0; t < 2; ++t) {
                    f16x8 bk = *(const f16x8*)(wq + (size_t)(256 + h * 32 + t * 16 + c) * 256 + kb);
                    #pragma unroll
                    for (int mi = 0; mi < 4; ++mi)
                        ak[t][mi] = __builtin_amdgcn_mfma_f32_16x16x32_f16(a[mi], bk, ak[t][mi], 0, 0, 0);
                }
            }
            #pragma unroll
            for (int mi = 0; mi < 4; ++mi) {
                #pragma unroll
                for (int r = 0; r < 4; ++r) {
                    float pk = ak[0][mi][r] * ak[0][mi][r] + ak[1][mi][r] * ak[1][mi][r];
                    pk += __shfl_xor(pk, 1); pk += __shfl_xor(pk, 2);
                    pk += __shfl_xor(pk, 4); pk += __shfl_xor(pk, 8);
                    float rk = __builtin_amdgcn_rsqf(fmaxf(pk, 1e-24f));
                    ak[0][mi][r] *= rk; ak[1][mi][r] *= rk;
                }
            }
            #pragma unroll
            for (int t = 0; t < 2; ++t)
                #pragma unroll
                for (int mi = 0; mi < 4; ++mi)
                    #pragma unroll
                    for (int r = 0; r < 4; ++r) {
                        int off = (mi * 16 + g * 4 + r) * 80 + (t * 16 + c) * 2;
                        *(f16*)(scr + off) = (f16)ak[t][mi][r];
                    }
            LGKM0();
            #pragma unroll
            for (int nj = 0; nj < 4; ++nj)
                kf[nj] = *(const f16x8*)(scr + (nj * 16 + c) * 80 + g * 16);
            LGKM0();
        }

        if (hh == 1) {
            // all x-reads block-wide are complete -> x-region becomes O-region
            __syncthreads(); // (2)
            const int h0 = w;
            #pragma unroll
            for (int mi = 0; mi < 4; ++mi)
                #pragma unroll
                for (int dt = 0; dt < 2; ++dt)
                    #pragma unroll
                    for (int r = 0; r < 4; ++r) {
                        int row = mi * 16 + g * 4 + r;
                        int col = h0 * 32 + dt * 16 + c;
                        int off = ((row << 9) + (col << 1)) ^ SWZ(row);
                        *(f16*)(lds + off) = po[mi][dt][r];
                    }
        }

        // ---- QK quarters -> exp -> P scratch, interleaved PV (+ ones-col rowsum) ----
        const float scl2e = sc[h] * L2E;
        const float* bbw = bb2 + h * 4096;
        f32x4 oo[4][2] = {};  // [mo][dt]
        f32x4 oaux[4] = {};   // ones-column: col-0 lanes accumulate rowsum
        f16 onev = (c == 0) ? (f16)1.f : (f16)0.f;
        f16x8 von = {onev, onev, onev, onev, onev, onev, onev, onev};
        #pragma unroll
        for (int nj = 0; nj < 4; ++nj) {
            #pragma unroll
            for (int mi = 0; mi < 4; ++mi) {
                f32x4 z = {};
                f32x4 s = __builtin_amdgcn_mfma_f32_16x16x32_f16(qf[mi], kf[nj], z, 0, 0, 0);
                f32x4 bb4 = *(const f32x4*)(bbw + mi * 1024 + nj * 256 + c * 16 + g * 4);
                #pragma unroll
                for (int r = 0; r < 4; ++r) {
                    float e = exp2f(fmaf(s[r], scl2e, bb4[r]));
                    int off = (mi * 16 + g * 4 + r) * 80 + (((nj & 1) * 16 + c) << 1);
                    *(f16*)(scr + off) = (f16)e;
                }
            }
            if (nj & 1) {
                const int kt = nj >> 1;
                LGKM0();
                f16x8 pa[4];
                #pragma unroll
                for (int mo = 0; mo < 4; ++mo)
                    pa[mo] = *(const f16x8*)(scr + (mo * 16 + c) * 80 + g * 16);
                LGKM0();
                #pragma unroll
                for (int mo = 0; mo < 4; ++mo) {
                    #pragma unroll
                    for (int dt = 0; dt < 2; ++dt)
                        oo[mo][dt] = __builtin_amdgcn_mfma_f32_16x16x32_f16(pa[mo], vf[dt][kt], oo[mo][dt], 0, 0, 0);
                    oaux[mo] = __builtin_amdgcn_mfma_f32_16x16x32_f16(pa[mo], von, oaux[mo], 0, 0, 0);
                }
            }
        }
        // rowsum broadcast from col-0 lane of each g-group; normalize O
        #pragma unroll
        for (int mo = 0; mo < 4; ++mo)
            #pragma unroll
            for (int r = 0; r < 4; ++r) {
                float rsum = __shfl(oaux[mo][r], lane & 48);
                float ri = __builtin_amdgcn_rcpf(rsum);
                oo[mo][0][r] *= ri;
                oo[mo][1][r] *= ri;
            }
        if (hh == 0) {
            #pragma unroll
            for (int mi = 0; mi < 4; ++mi)
                #pragma unroll
                for (int dt = 0; dt < 2; ++dt)
                    #pragma unroll
                    for (int r = 0; r < 4; ++r)
                        po[mi][dt][r] = (f16)oo[mi][dt][r];
        } else {
            #pragma unroll
            for (int mi = 0; mi < 4; ++mi)
                #pragma unroll
                for (int dt = 0; dt < 2; ++dt)
                    #pragma unroll
                    for (int r = 0; r < 4; ++r) {
                        int row = mi * 16 + g * 4 + r;
                        int col = h * 32 + dt * 16 + c;
                        int off = ((row << 9) + (col << 1)) ^ SWZ(row);
                        *(f16*)(lds + off) = (f16)oo[mi][dt][r];
                    }
        }
    }
    __syncthreads(); // (3) O complete -> proj may read

    // ---- proj GEMM: wave w -> out cols [64w, 64w+64) ----
    float pbias[4];
    #pragma unroll
    for (int nt = 0; nt < 4; ++nt) pbias[nt] = pb[w * 64 + nt * 16 + c];
    f32x4 pacc[4][4] = {}; // [nt][mi]
    #pragma unroll 2
    for (int kk = 0; kk < 8; ++kk) {
        int kb = kk * 32 + g * 8;
        f16x8 a[4];
        #pragma unroll
        for (int mi = 0; mi < 4; ++mi) {
            int row = mi * 16 + c;
            int off = ((row << 9) + (kb << 1)) ^ SWZ(row);
            a[mi] = *(const f16x8*)(lds + off);
        }
        #pragma unroll
        for (int nt = 0; nt < 4; ++nt) {
            f16x8 b = *(const f16x8*)(pw + (size_t)(w * 64 + nt * 16 + c) * 256 + kb);
            #pragma unroll
            for (int mi = 0; mi < 4; ++mi)
                pacc[nt][mi] = __builtin_amdgcn_mfma_f32_16x16x32_f16(a[mi], b, pacc[nt][mi], 0, 0, 0);
        }
    }
    __syncthreads(); // (4) all LDS dead -> f32 staging may overwrite

    // ---- 2-pass f32 staging (32 rows each) + full-line float4 writes ----
    #pragma unroll
    for (int p = 0; p < 2; ++p) {
        #pragma unroll
        for (int nt = 0; nt < 4; ++nt)
            #pragma unroll
            for (int m2 = 0; m2 < 2; ++m2) {
                int mi = p * 2 + m2;
                #pragma unroll
                for (int r = 0; r < 4; ++r) {
                    int row = m2 * 16 + g * 4 + r;         // 0..31 within pass
                    int col = w * 64 + nt * 16 + c;
                    int off = (row * 1024 + col * 4) ^ ((row & 7) << 4);
                    *(float*)(lds + off) = pacc[nt][mi][r] + pbias[nt];
                }
            }
        __syncthreads(); // (5)/(7)
        float4* out4 = (float4*)(out + (size_t)win * 16384 + p * 8192);
        #pragma unroll
        for (int it = 0; it < 8; ++it) {
            int e4 = it * 256 + tid;                       // 2048 float4 per pass
            int off = (e4 * 16) ^ (((e4 >> 6) & 7) << 4);
            out4[e4] = *(const float4*)(lds + off);
        }
        if (p == 0) __syncthreads(); // (6) pass-A reads done before overwrite
    }
}

// ---------------- launch ----------------

extern "C" void kernel_launch(void* const* d_in, const int* in_sizes, int n_in,
                              void* d_out, int out_size, void* d_ws, size_t ws_size,
                              hipStream_t stream) {
    (void)in_sizes; (void)n_in; (void)out_size; (void)ws_size;
    const float* x   = (const float*)d_in[0];
    const float* qw  = (const float*)d_in[1];
    const float* qb_ = (const float*)d_in[2];
    const float* vb_ = (const float*)d_in[3];
    const float* ls  = (const float*)d_in[4];
    const float* w1  = (const float*)d_in[5];
    const float* b1  = (const float*)d_in[6];
    const float* w2  = (const float*)d_in[7];
    const float* prw = (const float*)d_in[8];
    const float* pb  = (const float*)d_in[9];
    float* out = (float*)d_out;
    char* ws = (char*)d_ws;

    prep0<<<1024, 256, 0, stream>>>(qw, prw, qb_, vb_, ls, ws);
    prep1<<<8, 256, 0, stream>>>(w1, b1, w2, ws);
    prep2<<<128, 256, 0, stream>>>(ws);

    (void)hipFuncSetAttribute((const void*)swin_fused,
                              hipFuncAttributeMaxDynamicSharedMemorySize, 53248);
    swin_fused<<<8192, 256, 53248, stream>>>(
        x,
        (const f16*)(ws + WQ_OFF), (const f16*)(ws + PW_OFF),
        (const float*)(ws + QB_OFF), (const float*)(ws + SC_OFF),
        (const float*)(ws + BB_OFF), pb, out);
}